// Round 3
// baseline (502.597 us; speedup 1.0000x reference)
//
#include <hip/hip_runtime.h>
#include <hip/hip_bf16.h>
#include <math.h>

#define N_TOK 2048
#define DIM   1024
#define FF    2048
#define NEXP  8
#define NSLOT (N_TOK * 2)

typedef __attribute__((ext_vector_type(8))) short short8;
typedef __attribute__((ext_vector_type(4))) float f32x4;
typedef _Float16 half_t;
typedef __attribute__((ext_vector_type(4))) _Float16 h16x4;

__device__ __forceinline__ unsigned short f2bf(float f) {
    unsigned int u = __float_as_uint(f);
    u += 0x7FFFu + ((u >> 16) & 1u);   // round-to-nearest-even
    return (unsigned short)(u >> 16);
}

// async global->LDS 16B: LDS dst = wave-uniform base + lane*16; global addr per-lane
#define GLOAD_LDS16(g, l) \
    __builtin_amdgcn_global_load_lds((const __attribute__((address_space(1))) unsigned int*)(g), \
                                     (__attribute__((address_space(3))) unsigned int*)(l), 16, 0, 0)

// ---------------- router ------------------------------------------------------
__global__ __launch_bounds__(256) void k_router(const float* __restrict__ x,
        const float* __restrict__ Wg, int* __restrict__ hdr,
        int* __restrict__ tok_e, float* __restrict__ tok_w) {
    int wave = threadIdx.x >> 6, lane = threadIdx.x & 63;
    int t = blockIdx.x * 4 + wave;
    float acc[NEXP];
#pragma unroll
    for (int e = 0; e < NEXP; ++e) acc[e] = 0.f;
    const float* xr = x + (size_t)t * DIM;
    for (int d = lane; d < DIM; d += 64) {
        float xv = xr[d];
        const float* wr = Wg + d * NEXP;
#pragma unroll
        for (int e = 0; e < NEXP; ++e) acc[e] += xv * wr[e];
    }
#pragma unroll
    for (int off = 32; off > 0; off >>= 1) {
#pragma unroll
        for (int e = 0; e < NEXP; ++e) acc[e] += __shfl_down(acc[e], off);
    }
    if (lane == 0) {
        int e0 = 0;
#pragma unroll
        for (int e = 1; e < NEXP; ++e) if (acc[e] > acc[e0]) e0 = e;
        int e1 = -1;
#pragma unroll
        for (int e = 0; e < NEXP; ++e) {
            if (e == e0) continue;
            if (e1 < 0 || acc[e] > acc[e1]) e1 = e;
        }
        float w0 = 1.f / (1.f + expf(acc[e1] - acc[e0]));
        tok_e[2 * t] = e0; tok_e[2 * t + 1] = e1;
        tok_w[2 * t] = w0; tok_w[2 * t + 1] = 1.f - w0;
        atomicAdd(&hdr[e0], 1);
        atomicAdd(&hdr[e1], 1);
    }
}

// ---------------- scan --------------------------------------------------------
__global__ void k_scan(int* hdr) {
    if (threadIdx.x == 0 && blockIdx.x == 0) {
        int s = 0;
        for (int e = 0; e < NEXP; ++e) {
            hdr[16 + e] = s;
            hdr[8 + e]  = s;
            s += hdr[e];
        }
        hdr[24] = s;
    }
}

// ---------------- assign: slots + gather x -> bf16 ----------------------------
__global__ __launch_bounds__(256) void k_assign(const float* __restrict__ x,
        int* __restrict__ hdr, const int* __restrict__ tok_e,
        int* __restrict__ tok_slot, unsigned short* __restrict__ xg) {
    __shared__ int sh[2];
    int t = blockIdx.x;
    if (threadIdx.x == 0) {
        int e0 = tok_e[2 * t], e1 = tok_e[2 * t + 1];
        int p0 = atomicAdd(&hdr[8 + e0], 1);
        int p1 = atomicAdd(&hdr[8 + e1], 1);
        tok_slot[2 * t] = p0; tok_slot[2 * t + 1] = p1;
        sh[0] = p0; sh[1] = p1;
    }
    __syncthreads();
    int s0 = sh[0], s1 = sh[1];
    const float4* xr = (const float4*)(x + (size_t)t * DIM);
    float4 v = xr[threadIdx.x];
    ushort4 b;
    b.x = f2bf(v.x); b.y = f2bf(v.y); b.z = f2bf(v.z); b.w = f2bf(v.w);
    ((ushort4*)(xg + (size_t)s0 * DIM))[threadIdx.x] = b;
    ((ushort4*)(xg + (size_t)s1 * DIM))[threadIdx.x] = b;
}

// ---------------- transpose+convert weights -> bf16, K-contiguous layout ------
// tsel 0: Win [D][F] -> WinT [F][D]; 1: Wsc same; 2: Wout [F][D]->[D][F]... (generic R x C -> C x R)
__global__ __launch_bounds__(256) void k_transpose(
        const float* __restrict__ Win, const float* __restrict__ Wsc,
        const float* __restrict__ Wout, unsigned short* __restrict__ WinT,
        unsigned short* __restrict__ WscT, unsigned short* __restrict__ WoutT) {
    int z = blockIdx.z, tsel = z >> 3, e = z & 7;
    int R = (tsel == 2) ? FF : DIM;    // input rows
    int C = (tsel == 2) ? DIM : FF;    // input cols
    int tr0 = blockIdx.y * 64, tc0 = blockIdx.x * 64;
    if (tr0 >= R || tc0 >= C) return;
    const float* src = ((tsel == 0) ? Win : (tsel == 1) ? Wsc : Wout) + (size_t)e * DIM * FF;
    unsigned short* dst = ((tsel == 0) ? WinT : (tsel == 1) ? WscT : WoutT) + (size_t)e * DIM * FF;
    __shared__ unsigned short T[64][68];   // 136B stride: aligned 8B writes, mild read conflict
    int t = threadIdx.x, tr = t >> 4, tc = (t & 15) * 4;
#pragma unroll
    for (int i = 0; i < 4; ++i) {
        int r = tr + i * 16;
        float4 v = *(const float4*)&src[(size_t)(tr0 + r) * C + tc0 + tc];
        ushort4 b;
        b.x = f2bf(v.x); b.y = f2bf(v.y); b.z = f2bf(v.z); b.w = f2bf(v.w);
        *(ushort4*)&T[r][tc] = b;
    }
    __syncthreads();
    int r4 = (t & 15) * 4;
#pragma unroll
    for (int i = 0; i < 4; ++i) {
        int c = tr + i * 16;               // output row = input col
        ushort4 b;
        b.x = T[r4][c]; b.y = T[r4 + 1][c]; b.z = T[r4 + 2][c]; b.w = T[r4 + 3][c];
        *(ushort4*)&dst[(size_t)(tc0 + c) * R + tr0 + r4] = b;
    }
}

// ---------------- expert dual-GEMM h & s + exact GELU -> inner (bf16) --------
// tile 128 x 64F, K-step 32, 4 waves 2x2 (wave 64m x 32f). Full-DMA staging in
// permuted-issue layout: (row R, kchunk q) at ushort off (R>>4)*512+q*128+(R&15)*8
// -> every frag ds_read_b128 is a contiguous 1KB wave read (conflict-free).
__global__ __launch_bounds__(256, 4) void k_expert_hs(
        const unsigned short* __restrict__ xg,
        const unsigned short* __restrict__ WinT, const unsigned short* __restrict__ WscT,
        const float* __restrict__ b_in, const float* __restrict__ b_sc,
        const int* __restrict__ hdr, unsigned short* __restrict__ inner) {
    int e = blockIdx.z;
    int cnt = hdr[e];
    int mtile = blockIdx.y;
    if (mtile * 128 >= cnt) return;
    int base = hdr[16 + e];
    int f0 = blockIdx.x * 64;

    __shared__ unsigned short As[8 * 512];   // 8KB: 128 rows x 32k
    __shared__ unsigned short Bh[4 * 512];   // 4KB: 64 f x 32k
    __shared__ unsigned short Bs[4 * 512];

    int tid = threadIdx.x;
    int wave = tid >> 6, lane = tid & 63;
    int lr = lane & 15, lq = lane >> 4;
    int wm = (wave >> 1) * 64, wf = (wave & 1) * 32;

    f32x4 acch[4][2], accs[4][2];
#pragma unroll
    for (int mi = 0; mi < 4; ++mi)
#pragma unroll
        for (int fi = 0; fi < 2; ++fi) {
            acch[mi][fi] = (f32x4){0.f, 0.f, 0.f, 0.f};
            accs[mi][fi] = (f32x4){0.f, 0.f, 0.f, 0.f};
        }

    const unsigned short* Arow = xg + (size_t)(base + mtile * 128) * DIM;
    // DMA lane map: row = 16*issue + lr, kchunk = lq
    const unsigned short* gA0 = Arow + (size_t)(wave * 16 + lr) * DIM + lq * 8;
    const unsigned short* gA1 = gA0 + (size_t)64 * DIM;
    const unsigned short* gBh = WinT + (size_t)e * DIM * FF + (size_t)(f0 + wave * 16 + lr) * DIM + lq * 8;
    const unsigned short* gBs = WscT + (size_t)e * DIM * FF + (size_t)(f0 + wave * 16 + lr) * DIM + lq * 8;
    unsigned short* lA0 = As + wave * 512;
    unsigned short* lA1 = As + (4 + wave) * 512;
    unsigned short* lBh = Bh + wave * 512;
    unsigned short* lBs = Bs + wave * 512;

    // frag read bases (ushort units)
    const unsigned short* rA  = As + (wm >> 4) * 512 + lq * 128 + lr * 8;
    const unsigned short* rBh = Bh + (wf >> 4) * 512 + lq * 128 + lr * 8;
    const unsigned short* rBs = Bs + (wf >> 4) * 512 + lq * 128 + lr * 8;

    for (int k0 = 0; k0 < DIM; k0 += 32) {
        __syncthreads();                       // prior frag reads done
        GLOAD_LDS16(gA0, lA0);
        GLOAD_LDS16(gA1, lA1);
        GLOAD_LDS16(gBh, lBh);
        GLOAD_LDS16(gBs, lBs);
        __syncthreads();                       // drains DMA
        gA0 += 32; gA1 += 32; gBh += 32; gBs += 32;

        short8 af[4], bhf[2], bsf[2];
#pragma unroll
        for (int mi = 0; mi < 4; ++mi)
            af[mi] = *(const short8*)(rA + mi * 512);
#pragma unroll
        for (int fi = 0; fi < 2; ++fi) {
            bhf[fi] = *(const short8*)(rBh + fi * 512);
            bsf[fi] = *(const short8*)(rBs + fi * 512);
        }
#pragma unroll
        for (int mi = 0; mi < 4; ++mi)
#pragma unroll
            for (int fi = 0; fi < 2; ++fi) {
                acch[mi][fi] = __builtin_amdgcn_mfma_f32_16x16x32_bf16(
                    af[mi], bhf[fi], acch[mi][fi], 0, 0, 0);
                accs[mi][fi] = __builtin_amdgcn_mfma_f32_16x16x32_bf16(
                    af[mi], bsf[fi], accs[mi][fi], 0, 0, 0);
            }
    }

#pragma unroll
    for (int fi = 0; fi < 2; ++fi) {
        int f = f0 + wf + fi * 16 + lr;
        float bi = b_in[e * FF + f];
        float bs2 = b_sc[e * FF + f];
#pragma unroll
        for (int mi = 0; mi < 4; ++mi) {
#pragma unroll
            for (int r = 0; r < 4; ++r) {
                int rl = wm + mi * 16 + lq * 4 + r;
                int grow = mtile * 128 + rl;
                if (grow < cnt) {
                    float h = acch[mi][fi][r] + bi;
                    float s = accs[mi][fi][r] + bs2;
                    float g = 0.5f * h * (1.f + erff(h * 0.70710678f));
                    inner[(size_t)(base + grow) * FF + f] = f2bf(g * s);
                }
            }
        }
    }
}

// ---------------- expert out-GEMM, split-K=2, fp16 partials, full-DMA ---------
// tile 128 x 128D, 4 waves 2x2 (wave 64x64)
__global__ __launch_bounds__(256, 4) void k_expert_out(
        const unsigned short* __restrict__ inner,
        const unsigned short* __restrict__ WoutT,
        const int* __restrict__ hdr, half_t* __restrict__ pbuf) {
    int e = blockIdx.z & 7;
    int ks = blockIdx.z >> 3;
    int cnt = hdr[e];
    int mtile = blockIdx.y;
    if (mtile * 128 >= cnt) return;
    int base = hdr[16 + e];
    int d0 = blockIdx.x * 128;

    __shared__ unsigned short As[8 * 512];   // 128 rows x 32k
    __shared__ unsigned short Bt[8 * 512];   // 128 d x 32k

    int tid = threadIdx.x;
    int wave = tid >> 6, lane = tid & 63;
    int lr = lane & 15, lq = lane >> 4;
    int wm = (wave >> 1) * 64, wn = (wave & 1) * 64;

    f32x4 acc[4][4];
#pragma unroll
    for (int mi = 0; mi < 4; ++mi)
#pragma unroll
        for (int ni = 0; ni < 4; ++ni) acc[mi][ni] = (f32x4){0.f, 0.f, 0.f, 0.f};

    int kbeg = ks * (FF / 2);
    const unsigned short* Arow = inner + (size_t)(base + mtile * 128) * FF;
    const unsigned short* gA0 = Arow + (size_t)(wave * 16 + lr) * FF + kbeg + lq * 8;
    const unsigned short* gA1 = gA0 + (size_t)64 * FF;
    const unsigned short* gB0 = WoutT + (size_t)e * DIM * FF + (size_t)(d0 + wave * 16 + lr) * FF + kbeg + lq * 8;
    const unsigned short* gB1 = gB0 + (size_t)64 * FF;
    unsigned short* lA0 = As + wave * 512;
    unsigned short* lA1 = As + (4 + wave) * 512;
    unsigned short* lB0 = Bt + wave * 512;
    unsigned short* lB1 = Bt + (4 + wave) * 512;

    const unsigned short* rA = As + (wm >> 4) * 512 + lq * 128 + lr * 8;
    const unsigned short* rB = Bt + (wn >> 4) * 512 + lq * 128 + lr * 8;

    for (int ki = 0; ki < FF / 2; ki += 32) {
        __syncthreads();
        GLOAD_LDS16(gA0, lA0);
        GLOAD_LDS16(gA1, lA1);
        GLOAD_LDS16(gB0, lB0);
        GLOAD_LDS16(gB1, lB1);
        __syncthreads();
        gA0 += 32; gA1 += 32; gB0 += 32; gB1 += 32;

        short8 af[4], bfm[4];
#pragma unroll
        for (int mi = 0; mi < 4; ++mi)
            af[mi] = *(const short8*)(rA + mi * 512);
#pragma unroll
        for (int ni = 0; ni < 4; ++ni)
            bfm[ni] = *(const short8*)(rB + ni * 512);
#pragma unroll
        for (int mi = 0; mi < 4; ++mi)
#pragma unroll
            for (int ni = 0; ni < 4; ++ni)
                acc[mi][ni] = __builtin_amdgcn_mfma_f32_16x16x32_bf16(
                    af[mi], bfm[ni], acc[mi][ni], 0, 0, 0);
    }

    half_t* P = pbuf + (size_t)ks * NSLOT * DIM;
#pragma unroll
    for (int ni = 0; ni < 4; ++ni) {
        int d = d0 + wn + ni * 16 + lr;
#pragma unroll
        for (int mi = 0; mi < 4; ++mi) {
#pragma unroll
            for (int r = 0; r < 4; ++r) {
                int rl = wm + mi * 16 + lq * 4 + r;
                int grow = mtile * 128 + rl;
                if (grow < cnt)
                    P[(size_t)(base + grow) * DIM + d] = (half_t)acc[mi][ni][r];
            }
        }
    }
}

// ---------------- combine -----------------------------------------------------
__global__ __launch_bounds__(256) void k_combine(const half_t* __restrict__ pbuf,
        const int* __restrict__ tok_slot, const int* __restrict__ tok_e,
        const float* __restrict__ tok_w, const float* __restrict__ b_out,
        float* __restrict__ out) {
    int t = blockIdx.x;
    int d = threadIdx.x * 4;
    int s0 = tok_slot[2 * t], s1 = tok_slot[2 * t + 1];
    int e0 = tok_e[2 * t], e1 = tok_e[2 * t + 1];
    float w0 = tok_w[2 * t], w1 = tok_w[2 * t + 1];
    const half_t* pA = pbuf;
    const half_t* pB = pbuf + (size_t)NSLOT * DIM;
    h16x4 a0 = *(const h16x4*)&pA[(size_t)s0 * DIM + d];
    h16x4 a1 = *(const h16x4*)&pB[(size_t)s0 * DIM + d];
    h16x4 c0 = *(const h16x4*)&pA[(size_t)s1 * DIM + d];
    h16x4 c1 = *(const h16x4*)&pB[(size_t)s1 * DIM + d];
    float4 b0 = *(const float4*)&b_out[e0 * DIM + d];
    float4 b1 = *(const float4*)&b_out[e1 * DIM + d];
    float4 r;
    r.x = w0 * ((float)a0.x + (float)a1.x + b0.x) + w1 * ((float)c0.x + (float)c1.x + b1.x);
    r.y = w0 * ((float)a0.y + (float)a1.y + b0.y) + w1 * ((float)c0.y + (float)c1.y + b1.y);
    r.z = w0 * ((float)a0.z + (float)a1.z + b0.z) + w1 * ((float)c0.z + (float)c1.z + b1.z);
    r.w = w0 * ((float)a0.w + (float)a1.w + b0.w) + w1 * ((float)c0.w + (float)c1.w + b1.w);
    *(float4*)&out[(size_t)t * DIM + d] = r;
}

extern "C" void kernel_launch(void* const* d_in, const int* in_sizes, int n_in,
                              void* d_out, int out_size, void* d_ws, size_t ws_size,
                              hipStream_t stream) {
    (void)in_sizes; (void)n_in; (void)out_size; (void)ws_size;
    const float* x    = (const float*)d_in[0];
    const float* Wg   = (const float*)d_in[1];
    const float* Win  = (const float*)d_in[2];
    const float* b_in = (const float*)d_in[3];
    const float* Wsc  = (const float*)d_in[4];
    const float* b_sc = (const float*)d_in[5];
    const float* Wout = (const float*)d_in[6];
    const float* b_out= (const float*)d_in[7];
    float* out = (float*)d_out;

    char* ws = (char*)d_ws;
    int*   hdr      = (int*)ws;
    int*   tok_e    = (int*)(ws + 256);
    float* tok_w    = (float*)(ws + 16640);
    int*   tok_slot = (int*)(ws + 33024);
    unsigned short* xg    = (unsigned short*)(ws + 65792);             // 8 MB
    unsigned short* inner = (unsigned short*)(ws + 8454400);           // 16 MB
    half_t*         pbuf  = (half_t*)        (ws + 25231616);          // 16 MB
    unsigned short* WinT  = (unsigned short*)(ws + 42008832);          // 32 MB
    unsigned short* WscT  = (unsigned short*)(ws + 75563264);          // 32 MB
    unsigned short* WoutT = (unsigned short*)(ws + 109117696);         // 32 MB

    hipMemsetAsync(hdr, 0, 256, stream);
    k_transpose<<<dim3(32, 32, 24), dim3(256), 0, stream>>>(Win, Wsc, Wout, WinT, WscT, WoutT);
    k_router<<<dim3(N_TOK / 4), dim3(256), 0, stream>>>(x, Wg, hdr, tok_e, tok_w);
    k_scan<<<dim3(1), dim3(64), 0, stream>>>(hdr);
    k_assign<<<dim3(N_TOK), dim3(256), 0, stream>>>(x, hdr, tok_e, tok_slot, xg);
    k_expert_hs<<<dim3(FF / 64, 16, NEXP), dim3(256), 0, stream>>>(xg, WinT, WscT, b_in, b_sc, hdr, inner);
    k_expert_out<<<dim3(DIM / 128, 16, NEXP * 2), dim3(256), 0, stream>>>(inner, WoutT, hdr, pbuf);
    k_combine<<<dim3(N_TOK), dim3(256), 0, stream>>>(pbuf, tok_slot, tok_e, tok_w, b_out, out);
}